// Round 3
// baseline (119.328 us; speedup 1.0000x reference)
//
#include <hip/hip_runtime.h>

typedef unsigned short u16;
typedef unsigned int u32;
typedef __attribute__((ext_vector_type(8))) short short8;
typedef __attribute__((ext_vector_type(4))) float f32x4;
typedef __attribute__((ext_vector_type(4))) unsigned short ushort4v;

// ---------- helpers ----------
__device__ __forceinline__ float bf2f(u16 u) {
    return __uint_as_float(((u32)u) << 16);
}
__device__ __forceinline__ u16 f2bf(float f) {
    u32 u = __float_as_uint(f);
    u += 0x7FFF + ((u >> 16) & 1);   // RNE
    return (u16)(u >> 16);
}
__device__ __forceinline__ short8 cvt8(float4 a, float4 b) {
    short8 r;
    r[0] = (short)f2bf(a.x); r[1] = (short)f2bf(a.y);
    r[2] = (short)f2bf(a.z); r[3] = (short)f2bf(a.w);
    r[4] = (short)f2bf(b.x); r[5] = (short)f2bf(b.y);
    r[6] = (short)f2bf(b.z); r[7] = (short)f2bf(b.w);
    return r;
}
// async global->LDS, 16B per lane; dst wave-uniform (HW adds lane*16)
__device__ __forceinline__ void stage16(const u16* g, u16* l) {
    __builtin_amdgcn_global_load_lds(
        (const __attribute__((address_space(1))) unsigned int*)g,
        (__attribute__((address_space(3))) unsigned int*)l, 16, 0, 0);
}

// ---------- K0: cvt + transpose: x fp32 [2][8192][512] -> xT bf16 [2][512][8192] ----------
__global__ __launch_bounds__(256) void cvt_t(const float* __restrict__ x,
                                             u16* __restrict__ xT) {
    __shared__ u16 tile[64][136];   // [n][c], pad 8
    const int t = threadIdx.x;
    const int ct = blockIdx.x & 3, nt = (blockIdx.x >> 2) & 127, b = blockIdx.x >> 9;
    const int r = t >> 2, c0 = (t & 3) * 32;
    const float* src = x + ((size_t)(b * 8192 + nt * 64 + r)) * 512 + ct * 128 + c0;
#pragma unroll
    for (int j = 0; j < 8; j += 2) {
        float4 v0 = *(const float4*)(src + j * 4);
        float4 v1 = *(const float4*)(src + j * 4 + 4);
        *(short8*)(&tile[r][c0 + j * 4]) = cvt8(v0, v1);
    }
    __syncthreads();
    const int c = t >> 1, half = t & 1;
    u16 vals[32];
#pragma unroll
    for (int i = 0; i < 32; ++i) vals[i] = tile[half * 32 + i][c];
    u16* dst = xT + ((size_t)(b * 512 + ct * 128 + c)) * 8192 + nt * 64 + half * 32;
#pragma unroll
    for (int j = 0; j < 4; ++j)
        *(int4*)(dst + j * 8) = *(int4*)(&vals[j * 8]);
}

// ---------- K1: colsum s[b][c] = sum_n x[b][n][c] (row sums of xT) ----------
__global__ __launch_bounds__(256) void colsum(const u16* __restrict__ xT,
                                              float* __restrict__ s) {
    const int row = blockIdx.x;          // b*512 + c
    const u16* base = xT + (size_t)row * 8192;
    const int t = threadIdx.x;
    float sum = 0.f;
#pragma unroll
    for (int i = 0; i < 4; ++i) {
        short8 v = *(const short8*)(base + i * 2048 + t * 8);
#pragma unroll
        for (int j = 0; j < 8; ++j) sum += bf2f((u16)v[j]);
    }
    for (int off = 32; off; off >>= 1) sum += __shfl_down(sum, off);
    __shared__ float ws4[4];
    if ((t & 63) == 0) ws4[t >> 6] = sum;
    __syncthreads();
    if (t == 0) s[row] = ws4[0] + ws4[1] + ws4[2] + ws4[3];
}

// ---------- shared GEMM core: 128x128 tile, K=512, BK=32, global_load_lds ----------
template <int STRIDE>
__device__ __forceinline__ void gemm_core(const u16* __restrict__ Ag,
                                          const u16* __restrict__ Bg,
                                          u16* As, u16* Bs, int t,
                                          f32x4 acc[4][4]) {
    const int wv = t >> 6, l = t & 63;
    const int lr = l & 15, lk = (l >> 4) * 8;
    const int wm = (wv >> 1) * 64, wn = (wv & 1) * 64;
    const int srow = l >> 2, scol = (l & 3) * 8;

    u16* Ad0 = As + (wv * 32) * 32;
    u16* Ad1 = As + (wv * 32 + 16) * 32;
    u16* Bd0 = Bs + (wv * 32) * 32;
    u16* Bd1 = Bs + (wv * 32 + 16) * 32;
    const u16* As0 = Ag + (size_t)(wv * 32 + srow) * STRIDE + scol;
    const u16* As1 = Ag + (size_t)(wv * 32 + 16 + srow) * STRIDE + scol;
    const u16* Bs0 = Bg + (size_t)(wv * 32 + srow) * STRIDE + scol;
    const u16* Bs1 = Bg + (size_t)(wv * 32 + 16 + srow) * STRIDE + scol;

    for (int k0 = 0; k0 < 512; k0 += 32) {
        stage16(As0 + k0, Ad0);
        stage16(As1 + k0, Ad1);
        stage16(Bs0 + k0, Bd0);
        stage16(Bs1 + k0, Bd1);
        __syncthreads();
        short8 af[4], bfr[4];
#pragma unroll
        for (int mi = 0; mi < 4; ++mi)
            af[mi] = *(const short8*)(As + (wm + mi * 16 + lr) * 32 + lk);
#pragma unroll
        for (int ni = 0; ni < 4; ++ni)
            bfr[ni] = *(const short8*)(Bs + (wn + ni * 16 + lr) * 32 + lk);
#pragma unroll
        for (int mi = 0; mi < 4; ++mi)
#pragma unroll
            for (int ni = 0; ni < 4; ++ni)
                acc[mi][ni] = __builtin_amdgcn_mfma_f32_16x16x32_bf16(
                    af[mi], bfr[ni], acc[mi][ni], 0, 0, 0);
        __syncthreads();
    }
}

// ---------- K2: syrk partials Spart[b][ks] = xT[:,ks-chunk] @ xT[:,ks-chunk]^T ----------
__global__ __launch_bounds__(256) void syrk(const u16* __restrict__ xT,
                                            u16* __restrict__ Spart) {
    __shared__ u16 As[128 * 32];
    __shared__ u16 Bs[128 * 32];
    const int t = threadIdx.x;
    const int ks = blockIdx.x & 15, rem = blockIdx.x >> 4;
    const int nt = rem & 3, mt = (rem >> 2) & 3, b = rem >> 4;
    const u16* Ag = xT + ((size_t)(b * 512 + mt * 128)) * 8192 + ks * 512;
    const u16* Bg = xT + ((size_t)(b * 512 + nt * 128)) * 8192 + ks * 512;

    f32x4 zz = {0.f, 0.f, 0.f, 0.f};
    f32x4 acc[4][4];
    for (int i = 0; i < 4; ++i)
        for (int j = 0; j < 4; ++j) acc[i][j] = zz;

    gemm_core<8192>(Ag, Bg, As, Bs, t, acc);

    const int l = t & 63, wv = t >> 6;
    const int lr = l & 15;
    const int wm = (wv >> 1) * 64, wn = (wv & 1) * 64;
    u16* out = Spart + ((size_t)(b * 16 + ks)) * 262144;
#pragma unroll
    for (int mi = 0; mi < 4; ++mi)
#pragma unroll
        for (int ni = 0; ni < 4; ++ni) {
            int col = nt * 128 + wn + ni * 16 + lr;
#pragma unroll
            for (int j = 0; j < 4; ++j) {
                int row = mt * 128 + wm + mi * 16 + (l >> 4) * 4 + j;
                out[(size_t)row * 512 + col] = f2bf(acc[mi][ni][j]);
            }
        }
}

// ---------- K3: reduce partials + centering -> S' bf16 [2][512][512] ----------
__global__ __launch_bounds__(256) void reduceS(const u16* __restrict__ Spart,
                                               const float* __restrict__ s,
                                               u16* __restrict__ Sbf) {
    const int b = blockIdx.x >> 9, m = blockIdx.x & 511;
    const int t = threadIdx.x;
    const float sm = s[b * 512 + m] * (1.0f / 8192.0f);
#pragma unroll
    for (int rep = 0; rep < 2; ++rep) {
        const int n = rep * 256 + t;
        float acc = 0.f;
#pragma unroll
        for (int ks = 0; ks < 16; ++ks)
            acc += bf2f(Spart[((size_t)(b * 16 + ks)) * 262144 + (size_t)m * 512 + n]);
        acc -= sm * s[b * 512 + n];
        Sbf[(size_t)b * 262144 + (size_t)m * 512 + n] = f2bf(acc);
    }
}

// ---------- K4: g = Wk_h S' Wv_h^T per (b,h), two-stage MFMA ----------
__global__ __launch_bounds__(256, 1) void g_mfma(const u16* __restrict__ Sbf,
                                                 const float* __restrict__ W,
                                                 float* __restrict__ gfull) {
    const int b = blockIdx.x >> 3, h = blockIdx.x & 7;
    const int t = threadIdx.x, w = t >> 6, l = t & 63;
    const int lr = l & 15, lk = (l >> 4) * 8;
    __shared__ u16 Ts[64 * 520];
    const float* Wk = W + (size_t)(512 + h * 64) * 512;
    const u16* Sb = Sbf + (size_t)b * 262144;
    const int c2b = w * 128;

    f32x4 zz = {0.f, 0.f, 0.f, 0.f};
    // phase 1: T = Wk_h (64x512) * S' (512x512), wave w owns cols [w*128, w*128+128)
    f32x4 tacc[4][8];
    for (int i = 0; i < 4; ++i)
        for (int j = 0; j < 8; ++j) tacc[i][j] = zz;
    for (int k0 = 0; k0 < 512; k0 += 32) {
        short8 af[4];
#pragma unroll
        for (int mi = 0; mi < 4; ++mi) {
            const float* p = Wk + (size_t)(mi * 16 + lr) * 512 + k0 + lk;
            af[mi] = cvt8(*(const float4*)p, *(const float4*)(p + 4));
        }
        short8 bfv[8];
#pragma unroll
        for (int ni = 0; ni < 8; ++ni)
            bfv[ni] = *(const short8*)(Sb + (size_t)(c2b + ni * 16 + lr) * 512 + k0 + lk);
#pragma unroll
        for (int mi = 0; mi < 4; ++mi)
#pragma unroll
            for (int ni = 0; ni < 8; ++ni)
                tacc[mi][ni] = __builtin_amdgcn_mfma_f32_16x16x32_bf16(
                    af[mi], bfv[ni], tacc[mi][ni], 0, 0, 0);
    }
    // phase 2: T -> LDS bf16 [64][520]
#pragma unroll
    for (int mi = 0; mi < 4; ++mi)
#pragma unroll
        for (int ni = 0; ni < 8; ++ni)
#pragma unroll
            for (int j = 0; j < 4; ++j)
                Ts[(mi * 16 + (l >> 4) * 4 + j) * 520 + c2b + ni * 16 + lr] =
                    f2bf(tacc[mi][ni][j]);
    __syncthreads();
    // phase 3: g = T (64x512) * Wv_h^T (512x64); wave w owns d-rows [w*16, w*16+16)
    const float* Wv = W + (size_t)(1024 + h * 64) * 512;
    f32x4 gacc[4] = {zz, zz, zz, zz};
    for (int k0 = 0; k0 < 512; k0 += 32) {
        short8 a = *(const short8*)(Ts + (w * 16 + lr) * 520 + k0 + lk);
#pragma unroll
        for (int ni = 0; ni < 4; ++ni) {
            const float* p = Wv + (size_t)(ni * 16 + lr) * 512 + k0 + lk;
            short8 bfv = cvt8(*(const float4*)p, *(const float4*)(p + 4));
            gacc[ni] = __builtin_amdgcn_mfma_f32_16x16x32_bf16(a, bfv, gacc[ni], 0, 0, 0);
        }
    }
#pragma unroll
    for (int ni = 0; ni < 4; ++ni)
#pragma unroll
        for (int j = 0; j < 4; ++j)
            gfull[((size_t)(b * 8 + h)) * 4096 + (w * 16 + (l >> 4) * 4 + j) * 64 +
                  ni * 16 + lr] = gacc[ni][j];
}

// ---------- K5: Wg[b][he][c] = sum_d Wq[h*64+d][c] * g[bh][d][e] (bf16 K-major) ----------
__global__ __launch_bounds__(256) void fold(const float* __restrict__ gfull,
                                            const float* __restrict__ W,
                                            u16* __restrict__ Wgb) {
    const int bh = blockIdx.x >> 3, cb = blockIdx.x & 7;
    const int b = bh >> 3, h = bh & 7;
    const int t = threadIdx.x;
    __shared__ float gs[4096];
    for (int i = t; i < 4096; i += 256) gs[i] = gfull[bh * 4096 + i];
    __syncthreads();
    const int c = cb * 64 + (t & 63);
    const int eg = (t >> 6) * 16;
    float acc[16];
#pragma unroll
    for (int j = 0; j < 16; ++j) acc[j] = 0.f;
    for (int d = 0; d < 64; ++d) {
        float w = W[(size_t)(h * 64 + d) * 512 + c];
#pragma unroll
        for (int j = 0; j < 16; ++j) acc[j] += w * gs[d * 64 + eg + j];
    }
#pragma unroll
    for (int j = 0; j < 16; ++j)
        Wgb[(size_t)(b * 512 + h * 64 + eg + j) * 512 + c] = f2bf(acc[j]);
}

// ---------- K6: z = scale/1024 + (x @ Wg)/1024, A reg-staged from fp32 x ----------
__global__ __launch_bounds__(256) void out_z(const float* __restrict__ x,
                                             const u16* __restrict__ Wgb,
                                             float* __restrict__ z) {
    __shared__ u16 As[128 * 32];
    __shared__ u16 Bs[128 * 32];
    const int t = threadIdx.x;
    const int m0 = blockIdx.x * 128;
    const int b = blockIdx.x >> 6;
    const int n0 = blockIdx.y * 128;
    const int wv = t >> 6, l = t & 63;
    const int lr = l & 15, lk = (l >> 4) * 8;
    const int wm = (wv >> 1) * 64, wn = (wv & 1) * 64;
    const int sr = t >> 2, sc = (t & 3) * 8;
    const float* Ag = x + (size_t)m0 * 512;
    const int srow = l >> 2, scol = (l & 3) * 8;
    u16* Bd0 = Bs + (wv * 32) * 32;
    u16* Bd1 = Bs + (wv * 32 + 16) * 32;
    const u16* Bgb = Wgb + (size_t)b * 262144 + (size_t)n0 * 512;
    const u16* Bs0 = Bgb + (size_t)(wv * 32 + srow) * 512 + scol;
    const u16* Bs1 = Bgb + (size_t)(wv * 32 + 16 + srow) * 512 + scol;

    f32x4 zz = {0.f, 0.f, 0.f, 0.f};
    f32x4 acc[4][4];
    for (int i = 0; i < 4; ++i)
        for (int j = 0; j < 4; ++j) acc[i][j] = zz;

    for (int k0 = 0; k0 < 512; k0 += 32) {
        const float* a0p = Ag + (size_t)sr * 512 + k0 + sc;
        const float* a1p = Ag + (size_t)(sr + 64) * 512 + k0 + sc;
        short8 r0 = cvt8(*(const float4*)a0p, *(const float4*)(a0p + 4));
        short8 r1 = cvt8(*(const float4*)a1p, *(const float4*)(a1p + 4));
        stage16(Bs0 + k0, Bd0);
        stage16(Bs1 + k0, Bd1);
        *(short8*)(As + sr * 32 + sc) = r0;
        *(short8*)(As + (sr + 64) * 32 + sc) = r1;
        __syncthreads();
        short8 af[4], bfr[4];
#pragma unroll
        for (int mi = 0; mi < 4; ++mi)
            af[mi] = *(const short8*)(As + (wm + mi * 16 + lr) * 32 + lk);
#pragma unroll
        for (int ni = 0; ni < 4; ++ni)
            bfr[ni] = *(const short8*)(Bs + (wn + ni * 16 + lr) * 32 + lk);
#pragma unroll
        for (int mi = 0; mi < 4; ++mi)
#pragma unroll
            for (int ni = 0; ni < 4; ++ni)
                acc[mi][ni] = __builtin_amdgcn_mfma_f32_16x16x32_bf16(
                    af[mi], bfr[ni], acc[mi][ni], 0, 0, 0);
        __syncthreads();
    }

#pragma unroll
    for (int mi = 0; mi < 4; ++mi)
#pragma unroll
        for (int ni = 0; ni < 4; ++ni) {
            int he = n0 + wn + ni * 16 + lr;
            int h = he >> 6, e = he & 63;
#pragma unroll
            for (int j = 0; j < 4; ++j) {
                int row = m0 + wm + mi * 16 + (l >> 4) * 4 + j;
                int nidx = row & 8191;
                z[((size_t)(b * 8 + h) * 8192 + nidx) * 64 + e] =
                    (acc[mi][ni][j] + 0.125f) * 0.0009765625f;
            }
        }
}

extern "C" void kernel_launch(void* const* d_in, const int* in_sizes, int n_in,
                              void* d_out, int out_size, void* d_ws, size_t ws_size,
                              hipStream_t stream) {
    const float* x = (const float*)d_in[0];   // [2,8192,512] fp32
    const float* W = (const float*)d_in[1];   // [1536,512] fp32
    float* z = (float*)d_out;                 // [2,8,8192,64] fp32

    char* ws = (char*)d_ws;
    u16* xT      = (u16*)(ws);                  // 33,554,432 B  [2][512][8192] bf16
    u16* Spart   = (u16*)(ws + 33554432);       // 16,777,216 B  [2][16][512][512] bf16
    u16* Sbf     = (u16*)(ws + 50331648);       //  1,048,576 B  [2][512][512] bf16
    float* ssum  = (float*)(ws + 51380224);     //      4,096 B  [2][512] f32
    float* gfull = (float*)(ws + 51384320);     //    262,144 B  [16][64][64] f32
    u16* Wgb     = (u16*)(ws + 51646464);       //  1,048,576 B  [2][512][512] bf16

    cvt_t<<<1024, 256, 0, stream>>>(x, xT);
    colsum<<<1024, 256, 0, stream>>>(xT, ssum);
    syrk<<<512, 256, 0, stream>>>(xT, Spart);
    reduceS<<<1024, 256, 0, stream>>>(Spart, ssum, Sbf);
    g_mfma<<<16, 256, 0, stream>>>(Sbf, W, gfull);
    fold<<<128, 256, 0, stream>>>(gfull, W, Wgb);
    out_z<<<dim3(128, 4), 256, 0, stream>>>(x, Wgb, z);
}

// Round 4
// 102.550 us; speedup vs baseline: 1.1636x; 1.1636x over previous
//
#include <hip/hip_runtime.h>

typedef unsigned short u16;
typedef unsigned int u32;
typedef __attribute__((ext_vector_type(8))) short short8;
typedef __attribute__((ext_vector_type(4))) float f32x4;
typedef __attribute__((ext_vector_type(4))) unsigned short ushort4v;

// ---------- helpers ----------
__device__ __forceinline__ float bf2f(u16 u) {
    return __uint_as_float(((u32)u) << 16);
}
__device__ __forceinline__ u16 f2bf(float f) {
    u32 u = __float_as_uint(f);
    u += 0x7FFF + ((u >> 16) & 1);   // RNE
    return (u16)(u >> 16);
}
__device__ __forceinline__ short8 cvt8(float4 a, float4 b) {
    short8 r;
    r[0] = (short)f2bf(a.x); r[1] = (short)f2bf(a.y);
    r[2] = (short)f2bf(a.z); r[3] = (short)f2bf(a.w);
    r[4] = (short)f2bf(b.x); r[5] = (short)f2bf(b.y);
    r[6] = (short)f2bf(b.z); r[7] = (short)f2bf(b.w);
    return r;
}
// async global->LDS, 16B per lane; dst wave-uniform (HW adds lane*16)
__device__ __forceinline__ void stage16(const u16* g, u16* l) {
    __builtin_amdgcn_global_load_lds(
        (const __attribute__((address_space(1))) unsigned int*)g,
        (__attribute__((address_space(3))) unsigned int*)l, 16, 0, 0);
}

// ---------- zero ssum ----------
__global__ __launch_bounds__(256) void zero_s(float* __restrict__ s) {
    s[blockIdx.x * 256 + threadIdx.x] = 0.f;
}

// ---------- K0: cvt + transpose + fused column-sum ----------
// x fp32 [2][8192][512] -> xT bf16 [2][512][8192]; ssum[b][c] += partial sums
__global__ __launch_bounds__(256) void cvt_t(const float* __restrict__ x,
                                             u16* __restrict__ xT,
                                             float* __restrict__ ssum) {
    __shared__ u16 tile[64][136];   // [n][c], pad 8
    const int t = threadIdx.x;
    const int ct = blockIdx.x & 3, nt = (blockIdx.x >> 2) & 127, b = blockIdx.x >> 9;
    const int r = t >> 2, c0 = (t & 3) * 32;
    const float* src = x + ((size_t)(b * 8192 + nt * 64 + r)) * 512 + ct * 128 + c0;
#pragma unroll
    for (int j = 0; j < 8; j += 2) {
        float4 v0 = *(const float4*)(src + j * 4);
        float4 v1 = *(const float4*)(src + j * 4 + 4);
        *(short8*)(&tile[r][c0 + j * 4]) = cvt8(v0, v1);
    }
    __syncthreads();
    const int c = t >> 1, half = t & 1;
    u16 vals[32];
    float psum = 0.f;
#pragma unroll
    for (int i = 0; i < 32; ++i) {
        vals[i] = tile[half * 32 + i][c];
        psum += bf2f(vals[i]);
    }
    u16* dst = xT + ((size_t)(b * 512 + ct * 128 + c)) * 8192 + nt * 64 + half * 32;
#pragma unroll
    for (int j = 0; j < 4; ++j)
        *(int4*)(dst + j * 8) = *(int4*)(&vals[j * 8]);
    psum += __shfl_xor(psum, 1);
    if ((t & 1) == 0) atomicAdd(&ssum[b * 512 + ct * 128 + c], psum);
}

// ---------- cvt only (for Wv) ----------
typedef __attribute__((ext_vector_type(4))) float float4v;
__global__ __launch_bounds__(256) void cvt_bf16(const float* __restrict__ in,
                                                u16* __restrict__ out, int n4) {
    int i = blockIdx.x * 256 + threadIdx.x;
    int stride = gridDim.x * 256;
    for (; i < n4; i += stride) {
        float4v v = ((const float4v*)in)[i];
        ushort4v r;
        r[0] = f2bf(v[0]); r[1] = f2bf(v[1]); r[2] = f2bf(v[2]); r[3] = f2bf(v[3]);
        ((ushort4v*)out)[i] = r;
    }
}

// ---------- shared GEMM core: 128x128 tile, BK=32, global_load_lds ----------
template <int STRIDE, int KLEN>
__device__ __forceinline__ void gemm_core(const u16* __restrict__ Ag,
                                          const u16* __restrict__ Bg,
                                          u16* As, u16* Bs, int t,
                                          f32x4 acc[4][4]) {
    const int wv = t >> 6, l = t & 63;
    const int lr = l & 15, lk = (l >> 4) * 8;
    const int wm = (wv >> 1) * 64, wn = (wv & 1) * 64;
    const int srow = l >> 2, scol = (l & 3) * 8;

    u16* Ad0 = As + (wv * 32) * 32;
    u16* Ad1 = As + (wv * 32 + 16) * 32;
    u16* Bd0 = Bs + (wv * 32) * 32;
    u16* Bd1 = Bs + (wv * 32 + 16) * 32;
    const u16* As0 = Ag + (size_t)(wv * 32 + srow) * STRIDE + scol;
    const u16* As1 = Ag + (size_t)(wv * 32 + 16 + srow) * STRIDE + scol;
    const u16* Bs0 = Bg + (size_t)(wv * 32 + srow) * STRIDE + scol;
    const u16* Bs1 = Bg + (size_t)(wv * 32 + 16 + srow) * STRIDE + scol;

    for (int k0 = 0; k0 < KLEN; k0 += 32) {
        stage16(As0 + k0, Ad0);
        stage16(As1 + k0, Ad1);
        stage16(Bs0 + k0, Bd0);
        stage16(Bs1 + k0, Bd1);
        __syncthreads();
        short8 af[4], bfr[4];
#pragma unroll
        for (int mi = 0; mi < 4; ++mi)
            af[mi] = *(const short8*)(As + (wm + mi * 16 + lr) * 32 + lk);
#pragma unroll
        for (int ni = 0; ni < 4; ++ni)
            bfr[ni] = *(const short8*)(Bs + (wn + ni * 16 + lr) * 32 + lk);
#pragma unroll
        for (int mi = 0; mi < 4; ++mi)
#pragma unroll
            for (int ni = 0; ni < 4; ++ni)
                acc[mi][ni] = __builtin_amdgcn_mfma_f32_16x16x32_bf16(
                    af[mi], bfr[ni], acc[mi][ni], 0, 0, 0);
        __syncthreads();
    }
}

// ---------- K1: syrk partials over 256-row n-chunks (32 chunks) ----------
__global__ __launch_bounds__(256) void syrk(const u16* __restrict__ xT,
                                            u16* __restrict__ Spart) {
    __shared__ u16 As[128 * 32];
    __shared__ u16 Bs[128 * 32];
    const int t = threadIdx.x;
    const int nt = blockIdx.x & 3, mt = (blockIdx.x >> 2) & 3;
    const int ks = (blockIdx.x >> 4) & 31, b = blockIdx.x >> 9;
    const u16* Ag = xT + ((size_t)(b * 512 + mt * 128)) * 8192 + ks * 256;
    const u16* Bg = xT + ((size_t)(b * 512 + nt * 128)) * 8192 + ks * 256;

    f32x4 zz = {0.f, 0.f, 0.f, 0.f};
    f32x4 acc[4][4];
    for (int i = 0; i < 4; ++i)
        for (int j = 0; j < 4; ++j) acc[i][j] = zz;

    gemm_core<8192, 256>(Ag, Bg, As, Bs, t, acc);

    const int l = t & 63, wv = t >> 6;
    const int lr = l & 15;
    const int wm = (wv >> 1) * 64, wn = (wv & 1) * 64;
    u16* out = Spart + ((size_t)(b * 32 + ks)) * 262144;
#pragma unroll
    for (int mi = 0; mi < 4; ++mi)
#pragma unroll
        for (int ni = 0; ni < 4; ++ni) {
            int col = nt * 128 + wn + ni * 16 + lr;
#pragma unroll
            for (int j = 0; j < 4; ++j) {
                int row = mt * 128 + wm + mi * 16 + (l >> 4) * 4 + j;
                out[(size_t)row * 512 + col] = f2bf(acc[mi][ni][j]);
            }
        }
}

// ---------- K2: reduce partials + centering -> S' bf16 [2][512][512] ----------
__global__ __launch_bounds__(256) void reduceS(const u16* __restrict__ Spart,
                                               const float* __restrict__ s,
                                               u16* __restrict__ Sbf) {
    const int b = blockIdx.x >> 9, m = blockIdx.x & 511;
    const int t = threadIdx.x;
    const float sm = s[b * 512 + m] * (1.0f / 8192.0f);
#pragma unroll
    for (int rep = 0; rep < 2; ++rep) {
        const int n = rep * 256 + t;
        float acc = 0.f;
        for (int ks = 0; ks < 32; ++ks)
            acc += bf2f(Spart[((size_t)(b * 32 + ks)) * 262144 + (size_t)m * 512 + n]);
        acc -= sm * s[b * 512 + n];
        Sbf[(size_t)b * 262144 + (size_t)m * 512 + n] = f2bf(acc);
    }
}

// ---------- K3: Ppart[b][ks] = Wv * S'_b (K-split x4), fp32 partials ----------
__global__ __launch_bounds__(256) void pgemm(const u16* __restrict__ wvb,
                                             const u16* __restrict__ Sbf,
                                             float* __restrict__ Ppart) {
    __shared__ u16 As[128 * 32];
    __shared__ u16 Bs[128 * 32];
    const int t = threadIdx.x;
    const int nt = blockIdx.x & 3, mt = (blockIdx.x >> 2) & 3;
    const int ks = (blockIdx.x >> 4) & 3, b = blockIdx.x >> 6;
    const u16* Ag = wvb + (size_t)(mt * 128) * 512 + ks * 128;
    const u16* Bg = Sbf + (size_t)b * 262144 + (size_t)(nt * 128) * 512 + ks * 128;

    f32x4 zz = {0.f, 0.f, 0.f, 0.f};
    f32x4 acc[4][4];
    for (int i = 0; i < 4; ++i)
        for (int j = 0; j < 4; ++j) acc[i][j] = zz;

    gemm_core<512, 128>(Ag, Bg, As, Bs, t, acc);

    const int l = t & 63, wv = t >> 6;
    const int lr = l & 15;
    const int wm = (wv >> 1) * 64, wn = (wv & 1) * 64;
    float* out = Ppart + ((size_t)(b * 4 + ks)) * 262144;
#pragma unroll
    for (int mi = 0; mi < 4; ++mi)
#pragma unroll
        for (int ni = 0; ni < 4; ++ni) {
            int col = nt * 128 + wn + ni * 16 + lr;
#pragma unroll
            for (int j = 0; j < 4; ++j) {
                int row = mt * 128 + wm + mi * 16 + (l >> 4) * 4 + j;
                out[(size_t)row * 512 + col] = acc[mi][ni][j];
            }
        }
}

// ---------- K4: reduce Ppart -> P bf16 [2][512][512] ----------
__global__ __launch_bounds__(256) void reduceP(const float* __restrict__ Ppart,
                                               u16* __restrict__ Pb) {
    int idx = blockIdx.x * 1024 + threadIdx.x;
    for (int r = 0; r < 4; ++r, idx += 256) {
        const int b = idx >> 18, rem = idx & 262143;
        float acc = 0.f;
#pragma unroll
        for (int ks = 0; ks < 4; ++ks)
            acc += Ppart[((size_t)(b * 4 + ks)) * 262144 + rem];
        Pb[idx] = f2bf(acc);
    }
}

// ---------- K5: g[bh][d][e] = sum_c Wk[h*64+d][c] * P[b][h*64+e][c] ----------
// grid = 16 bh * 4 e-tiles; block = 4 waves (wave w -> d-rows w*16..)
__global__ __launch_bounds__(256) void g2(const float* __restrict__ W,
                                          const u16* __restrict__ Pb,
                                          float* __restrict__ gfull) {
    const int bh = blockIdx.x >> 2, nt = blockIdx.x & 3;
    const int b = bh >> 3, h = bh & 7;
    const int t = threadIdx.x, w = t >> 6, l = t & 63;
    const int lr = l & 15, lk = (l >> 4) * 8;
    const float* Wk = W + (size_t)(512 + h * 64 + w * 16 + lr) * 512;
    const u16* Pr = Pb + (size_t)b * 262144 + (size_t)(h * 64 + nt * 16 + lr) * 512;

    f32x4 acc = {0.f, 0.f, 0.f, 0.f};
    for (int k0 = 0; k0 < 512; k0 += 32) {
        short8 af = cvt8(*(const float4*)(Wk + k0 + lk),
                         *(const float4*)(Wk + k0 + lk + 4));
        short8 bfr = *(const short8*)(Pr + k0 + lk);
        acc = __builtin_amdgcn_mfma_f32_16x16x32_bf16(af, bfr, acc, 0, 0, 0);
    }
#pragma unroll
    for (int j = 0; j < 4; ++j) {
        int d = w * 16 + (l >> 4) * 4 + j;
        int e = nt * 16 + lr;
        gfull[(size_t)bh * 4096 + d * 64 + e] = acc[j];
    }
}

// ---------- K6: Wg[b][he][c] = sum_d Wq[h*64+d][c] * g[bh][d][e] (bf16 K-major) ----------
__global__ __launch_bounds__(256) void fold(const float* __restrict__ gfull,
                                            const float* __restrict__ W,
                                            u16* __restrict__ Wgb) {
    const int bh = blockIdx.x >> 3, cb = blockIdx.x & 7;
    const int b = bh >> 3, h = bh & 7;
    const int t = threadIdx.x;
    __shared__ float gs[4096];
    for (int i = t; i < 4096; i += 256) gs[i] = gfull[bh * 4096 + i];
    __syncthreads();
    const int c = cb * 64 + (t & 63);
    const int eg = (t >> 6) * 16;
    float acc[16];
#pragma unroll
    for (int j = 0; j < 16; ++j) acc[j] = 0.f;
    for (int d = 0; d < 64; ++d) {
        float w = W[(size_t)(h * 64 + d) * 512 + c];
#pragma unroll
        for (int j = 0; j < 16; ++j) acc[j] += w * gs[d * 64 + eg + j];
    }
#pragma unroll
    for (int j = 0; j < 16; ++j)
        Wgb[(size_t)(b * 512 + h * 64 + eg + j) * 512 + c] = f2bf(acc[j]);
}

// ---------- K7: z = scale/1024 + (x @ Wg)/1024, A reg-staged from fp32 x ----------
__global__ __launch_bounds__(256) void out_z(const float* __restrict__ x,
                                             const u16* __restrict__ Wgb,
                                             float* __restrict__ z) {
    __shared__ u16 As[128 * 32];
    __shared__ u16 Bs[128 * 32];
    const int t = threadIdx.x;
    const int m0 = blockIdx.x * 128;
    const int b = blockIdx.x >> 6;
    const int n0 = blockIdx.y * 128;
    const int wv = t >> 6, l = t & 63;
    const int lr = l & 15, lk = (l >> 4) * 8;
    const int wm = (wv >> 1) * 64, wn = (wv & 1) * 64;
    const int sr = t >> 2, sc = (t & 3) * 8;
    const float* Ag = x + (size_t)m0 * 512;
    const int srow = l >> 2, scol = (l & 3) * 8;
    u16* Bd0 = Bs + (wv * 32) * 32;
    u16* Bd1 = Bs + (wv * 32 + 16) * 32;
    const u16* Bgb = Wgb + (size_t)b * 262144 + (size_t)n0 * 512;
    const u16* Bs0 = Bgb + (size_t)(wv * 32 + srow) * 512 + scol;
    const u16* Bs1 = Bgb + (size_t)(wv * 32 + 16 + srow) * 512 + scol;

    f32x4 zz = {0.f, 0.f, 0.f, 0.f};
    f32x4 acc[4][4];
    for (int i = 0; i < 4; ++i)
        for (int j = 0; j < 4; ++j) acc[i][j] = zz;

    for (int k0 = 0; k0 < 512; k0 += 32) {
        const float* a0p = Ag + (size_t)sr * 512 + k0 + sc;
        const float* a1p = Ag + (size_t)(sr + 64) * 512 + k0 + sc;
        short8 r0 = cvt8(*(const float4*)a0p, *(const float4*)(a0p + 4));
        short8 r1 = cvt8(*(const float4*)a1p, *(const float4*)(a1p + 4));
        stage16(Bs0 + k0, Bd0);
        stage16(Bs1 + k0, Bd1);
        *(short8*)(As + sr * 32 + sc) = r0;
        *(short8*)(As + (sr + 64) * 32 + sc) = r1;
        __syncthreads();
        short8 af[4], bfr[4];
#pragma unroll
        for (int mi = 0; mi < 4; ++mi)
            af[mi] = *(const short8*)(As + (wm + mi * 16 + lr) * 32 + lk);
#pragma unroll
        for (int ni = 0; ni < 4; ++ni)
            bfr[ni] = *(const short8*)(Bs + (wn + ni * 16 + lr) * 32 + lk);
#pragma unroll
        for (int mi = 0; mi < 4; ++mi)
#pragma unroll
            for (int ni = 0; ni < 4; ++ni)
                acc[mi][ni] = __builtin_amdgcn_mfma_f32_16x16x32_bf16(
                    af[mi], bfr[ni], acc[mi][ni], 0, 0, 0);
        __syncthreads();
    }

#pragma unroll
    for (int mi = 0; mi < 4; ++mi)
#pragma unroll
        for (int ni = 0; ni < 4; ++ni) {
            int he = n0 + wn + ni * 16 + lr;
            int h = he >> 6, e = he & 63;
#pragma unroll
            for (int j = 0; j < 4; ++j) {
                int row = m0 + wm + mi * 16 + (l >> 4) * 4 + j;
                int nidx = row & 8191;
                z[((size_t)(b * 8 + h) * 8192 + nidx) * 64 + e] =
                    (acc[mi][ni][j] + 0.125f) * 0.0009765625f;
            }
        }
}

extern "C" void kernel_launch(void* const* d_in, const int* in_sizes, int n_in,
                              void* d_out, int out_size, void* d_ws, size_t ws_size,
                              hipStream_t stream) {
    const float* x = (const float*)d_in[0];   // [2,8192,512] fp32
    const float* W = (const float*)d_in[1];   // [1536,512] fp32
    float* z = (float*)d_out;                 // [2,8,8192,64] fp32

    char* ws = (char*)d_ws;
    u16* xT      = (u16*)(ws);                  // 33,554,432 B  [2][512][8192]
    u16* Spart   = (u16*)(ws + 33554432);       // 33,554,432 B  [2][32][512][512]
    u16* Sbf     = (u16*)(ws + 67108864);       //  1,048,576 B  [2][512][512]
    float* ssum  = (float*)(ws + 68157440);     //      4,096 B  [2][512]
    u16* wvb     = (u16*)(ws + 68161536);       //    524,288 B  [512][512]
    float* Ppart = (float*)(ws + 68685824);     //  8,388,608 B  [2][4][512][512]
    u16* Pb      = (u16*)(ws + 77074432);       //  1,048,576 B  [2][512][512]
    float* gfull = (float*)(ws + 78123008);     //    262,144 B  [16][64][64]
    u16* Wgb     = (u16*)(ws + 78385152);       //  1,048,576 B  [2][512][512]

    zero_s<<<4, 256, 0, stream>>>(ssum);
    cvt_t<<<1024, 256, 0, stream>>>(x, xT, ssum);
    cvt_bf16<<<256, 256, 0, stream>>>(W + 524288, wvb, 65536);  // Wv rows
    syrk<<<1024, 256, 0, stream>>>(xT, Spart);
    reduceS<<<1024, 256, 0, stream>>>(Spart, ssum, Sbf);
    pgemm<<<128, 256, 0, stream>>>(wvb, Sbf, Ppart);
    reduceP<<<512, 256, 0, stream>>>(Ppart, Pb);
    g2<<<64, 256, 0, stream>>>(W, Pb, gfull);
    fold<<<128, 256, 0, stream>>>(gfull, W, Wgb);
    out_z<<<dim3(128, 4), 256, 0, stream>>>(x, Wgb, z);
}

// Round 6
// 101.402 us; speedup vs baseline: 1.1768x; 1.0113x over previous
//
#include <hip/hip_runtime.h>

typedef unsigned short u16;
typedef unsigned int u32;
typedef __attribute__((ext_vector_type(8))) short short8;
typedef __attribute__((ext_vector_type(4))) float f32x4;
typedef __attribute__((ext_vector_type(4))) unsigned short ushort4v;

// ---------- helpers ----------
__device__ __forceinline__ float bf2f(u16 u) {
    return __uint_as_float(((u32)u) << 16);
}
__device__ __forceinline__ u16 f2bf(float f) {
    u32 u = __float_as_uint(f);
    u += 0x7FFF + ((u >> 16) & 1);   // RNE
    return (u16)(u >> 16);
}
__device__ __forceinline__ short8 cvt8(float4 a, float4 b) {
    short8 r;
    r[0] = (short)f2bf(a.x); r[1] = (short)f2bf(a.y);
    r[2] = (short)f2bf(a.z); r[3] = (short)f2bf(a.w);
    r[4] = (short)f2bf(b.x); r[5] = (short)f2bf(b.y);
    r[6] = (short)f2bf(b.z); r[7] = (short)f2bf(b.w);
    return r;
}
// async global->LDS, 16B per lane; dst wave-uniform (HW adds lane*16)
__device__ __forceinline__ void stage16(const u16* g, u16* l) {
    __builtin_amdgcn_global_load_lds(
        (const __attribute__((address_space(1))) unsigned int*)g,
        (__attribute__((address_space(3))) unsigned int*)l, 16, 0, 0);
}

// ---------- zero ssum ----------
__global__ __launch_bounds__(256) void zero_s(float* __restrict__ s) {
    s[blockIdx.x * 256 + threadIdx.x] = 0.f;
}

// ---------- K0: cvt + transpose + row-major bf16 copy + fused column-sum ----------
// x fp32 [2][8192][512] -> xT bf16 [2][512][8192], xb bf16 [2][8192][512]; ssum += partials
__global__ __launch_bounds__(256) void cvt_t(const float* __restrict__ x,
                                             u16* __restrict__ xT,
                                             u16* __restrict__ xb,
                                             float* __restrict__ ssum) {
    __shared__ u16 tile[64][136];   // [n][c], pad 8
    const int t = threadIdx.x;
    const int ct = blockIdx.x & 3, nt = (blockIdx.x >> 2) & 127, b = blockIdx.x >> 9;
    const int r = t >> 2, c0 = (t & 3) * 32;
    const float* src = x + ((size_t)(b * 8192 + nt * 64 + r)) * 512 + ct * 128 + c0;
    short8 r8[4];
#pragma unroll
    for (int j = 0; j < 8; j += 2) {
        float4 v0 = *(const float4*)(src + j * 4);
        float4 v1 = *(const float4*)(src + j * 4 + 4);
        r8[j >> 1] = cvt8(v0, v1);
        *(short8*)(&tile[r][c0 + j * 4]) = r8[j >> 1];
    }
    // row-major bf16 copy (64B per thread, contiguous within 4-lane groups)
    u16* xbrow = xb + ((size_t)(b * 8192 + nt * 64 + r)) * 512 + ct * 128 + c0;
#pragma unroll
    for (int jj = 0; jj < 4; ++jj) *(short8*)(xbrow + jj * 8) = r8[jj];
    __syncthreads();
    const int c = t >> 1, half = t & 1;
    u16 vals[32];
    float psum = 0.f;
#pragma unroll
    for (int i = 0; i < 32; ++i) {
        vals[i] = tile[half * 32 + i][c];
        psum += bf2f(vals[i]);
    }
    u16* dst = xT + ((size_t)(b * 512 + ct * 128 + c)) * 8192 + nt * 64 + half * 32;
#pragma unroll
    for (int j = 0; j < 4; ++j)
        *(int4*)(dst + j * 8) = *(int4*)(&vals[j * 8]);
    psum += __shfl_xor(psum, 1);
    if ((t & 1) == 0) atomicAdd(&ssum[b * 512 + ct * 128 + c], psum);
}

// ---------- cvt only (for Wv) ----------
typedef __attribute__((ext_vector_type(4))) float float4v;
__global__ __launch_bounds__(256) void cvt_bf16(const float* __restrict__ in,
                                                u16* __restrict__ out, int n4) {
    int i = blockIdx.x * 256 + threadIdx.x;
    int stride = gridDim.x * 256;
    for (; i < n4; i += stride) {
        float4v v = ((const float4v*)in)[i];
        ushort4v r;
        r[0] = f2bf(v[0]); r[1] = f2bf(v[1]); r[2] = f2bf(v[2]); r[3] = f2bf(v[3]);
        ((ushort4v*)out)[i] = r;
    }
}

// ---------- shared GEMM core: 128x128 tile, BK=32, global_load_lds ----------
template <int STRIDE, int KLEN>
__device__ __forceinline__ void gemm_core(const u16* __restrict__ Ag,
                                          const u16* __restrict__ Bg,
                                          u16* As, u16* Bs, int t,
                                          f32x4 acc[4][4]) {
    const int wv = t >> 6, l = t & 63;
    const int lr = l & 15, lk = (l >> 4) * 8;
    const int wm = (wv >> 1) * 64, wn = (wv & 1) * 64;
    const int srow = l >> 2, scol = (l & 3) * 8;

    u16* Ad0 = As + (wv * 32) * 32;
    u16* Ad1 = As + (wv * 32 + 16) * 32;
    u16* Bd0 = Bs + (wv * 32) * 32;
    u16* Bd1 = Bs + (wv * 32 + 16) * 32;
    const u16* As0 = Ag + (size_t)(wv * 32 + srow) * STRIDE + scol;
    const u16* As1 = Ag + (size_t)(wv * 32 + 16 + srow) * STRIDE + scol;
    const u16* Bs0 = Bg + (size_t)(wv * 32 + srow) * STRIDE + scol;
    const u16* Bs1 = Bg + (size_t)(wv * 32 + 16 + srow) * STRIDE + scol;

    for (int k0 = 0; k0 < KLEN; k0 += 32) {
        stage16(As0 + k0, Ad0);
        stage16(As1 + k0, Ad1);
        stage16(Bs0 + k0, Bd0);
        stage16(Bs1 + k0, Bd1);
        __syncthreads();
        short8 af[4], bfr[4];
#pragma unroll
        for (int mi = 0; mi < 4; ++mi)
            af[mi] = *(const short8*)(As + (wm + mi * 16 + lr) * 32 + lk);
#pragma unroll
        for (int ni = 0; ni < 4; ++ni)
            bfr[ni] = *(const short8*)(Bs + (wn + ni * 16 + lr) * 32 + lk);
#pragma unroll
        for (int mi = 0; mi < 4; ++mi)
#pragma unroll
            for (int ni = 0; ni < 4; ++ni)
                acc[mi][ni] = __builtin_amdgcn_mfma_f32_16x16x32_bf16(
                    af[mi], bfr[ni], acc[mi][ni], 0, 0, 0);
        __syncthreads();
    }
}

// ---------- K1: syrk partials over 256-row n-chunks (32 chunks) ----------
__global__ __launch_bounds__(256) void syrk(const u16* __restrict__ xT,
                                            u16* __restrict__ Spart) {
    __shared__ u16 As[128 * 32];
    __shared__ u16 Bs[128 * 32];
    const int t = threadIdx.x;
    const int nt = blockIdx.x & 3, mt = (blockIdx.x >> 2) & 3;
    const int ks = (blockIdx.x >> 4) & 31, b = blockIdx.x >> 9;
    const u16* Ag = xT + ((size_t)(b * 512 + mt * 128)) * 8192 + ks * 256;
    const u16* Bg = xT + ((size_t)(b * 512 + nt * 128)) * 8192 + ks * 256;

    f32x4 zz = {0.f, 0.f, 0.f, 0.f};
    f32x4 acc[4][4];
    for (int i = 0; i < 4; ++i)
        for (int j = 0; j < 4; ++j) acc[i][j] = zz;

    gemm_core<8192, 256>(Ag, Bg, As, Bs, t, acc);

    const int l = t & 63, wv = t >> 6;
    const int lr = l & 15;
    const int wm = (wv >> 1) * 64, wn = (wv & 1) * 64;
    u16* out = Spart + ((size_t)(b * 32 + ks)) * 262144;
#pragma unroll
    for (int mi = 0; mi < 4; ++mi)
#pragma unroll
        for (int ni = 0; ni < 4; ++ni) {
            int col = nt * 128 + wn + ni * 16 + lr;
#pragma unroll
            for (int j = 0; j < 4; ++j) {
                int row = mt * 128 + wm + mi * 16 + (l >> 4) * 4 + j;
                out[(size_t)row * 512 + col] = f2bf(acc[mi][ni][j]);
            }
        }
}

// ---------- K2: reduce partials + centering -> S' bf16 [2][512][512] ----------
__global__ __launch_bounds__(256) void reduceS(const u16* __restrict__ Spart,
                                               const float* __restrict__ s,
                                               u16* __restrict__ Sbf) {
    const int b = blockIdx.x >> 9, m = blockIdx.x & 511;
    const int t = threadIdx.x;
    const float sm = s[b * 512 + m] * (1.0f / 8192.0f);
#pragma unroll
    for (int rep = 0; rep < 2; ++rep) {
        const int n = rep * 256 + t;
        float acc = 0.f;
        for (int ks = 0; ks < 32; ++ks)
            acc += bf2f(Spart[((size_t)(b * 32 + ks)) * 262144 + (size_t)m * 512 + n]);
        acc -= sm * s[b * 512 + n];
        Sbf[(size_t)b * 262144 + (size_t)m * 512 + n] = f2bf(acc);
    }
}

// ---------- K3: Ppart[b][ks] = Wv * S'_b (K-split x4), fp32 partials ----------
__global__ __launch_bounds__(256) void pgemm(const u16* __restrict__ wvb,
                                             const u16* __restrict__ Sbf,
                                             float* __restrict__ Ppart) {
    __shared__ u16 As[128 * 32];
    __shared__ u16 Bs[128 * 32];
    const int t = threadIdx.x;
    const int nt = blockIdx.x & 3, mt = (blockIdx.x >> 2) & 3;
    const int ks = (blockIdx.x >> 4) & 3, b = blockIdx.x >> 6;
    const u16* Ag = wvb + (size_t)(mt * 128) * 512 + ks * 128;
    const u16* Bg = Sbf + (size_t)b * 262144 + (size_t)(nt * 128) * 512 + ks * 128;

    f32x4 zz = {0.f, 0.f, 0.f, 0.f};
    f32x4 acc[4][4];
    for (int i = 0; i < 4; ++i)
        for (int j = 0; j < 4; ++j) acc[i][j] = zz;

    gemm_core<512, 128>(Ag, Bg, As, Bs, t, acc);

    const int l = t & 63, wv = t >> 6;
    const int lr = l & 15;
    const int wm = (wv >> 1) * 64, wn = (wv & 1) * 64;
    float* out = Ppart + ((size_t)(b * 4 + ks)) * 262144;
#pragma unroll
    for (int mi = 0; mi < 4; ++mi)
#pragma unroll
        for (int ni = 0; ni < 4; ++ni) {
            int col = nt * 128 + wn + ni * 16 + lr;
#pragma unroll
            for (int j = 0; j < 4; ++j) {
                int row = mt * 128 + wm + mi * 16 + (l >> 4) * 4 + j;
                out[(size_t)row * 512 + col] = acc[mi][ni][j];
            }
        }
}

// ---------- K4: reduce Ppart -> P bf16 [2][512][512] ----------
__global__ __launch_bounds__(256) void reduceP(const float* __restrict__ Ppart,
                                               u16* __restrict__ Pb) {
    int idx = blockIdx.x * 1024 + threadIdx.x;
    for (int r = 0; r < 4; ++r, idx += 256) {
        const int b = idx >> 18, rem = idx & 262143;
        float acc = 0.f;
#pragma unroll
        for (int ks = 0; ks < 4; ++ks)
            acc += Ppart[((size_t)(b * 4 + ks)) * 262144 + rem];
        Pb[idx] = f2bf(acc);
    }
}

// ---------- K5: g[bh][d][e] = sum_c Wk[h*64+d][c] * P[b][h*64+e][c] ----------
// grid = 16 bh * 4 e-tiles; block = 4 waves (wave w -> d-rows w*16..)
__global__ __launch_bounds__(256) void g2(const float* __restrict__ W,
                                          const u16* __restrict__ Pb,
                                          float* __restrict__ gfull) {
    const int bh = blockIdx.x >> 2, nt = blockIdx.x & 3;
    const int b = bh >> 3, h = bh & 7;
    const int t = threadIdx.x, w = t >> 6, l = t & 63;
    const int lr = l & 15, lk = (l >> 4) * 8;
    const float* Wk = W + (size_t)(512 + h * 64 + w * 16 + lr) * 512;
    const u16* Pr = Pb + (size_t)b * 262144 + (size_t)(h * 64 + nt * 16 + lr) * 512;

    f32x4 acc = {0.f, 0.f, 0.f, 0.f};
    for (int k0 = 0; k0 < 512; k0 += 32) {
        short8 af = cvt8(*(const float4*)(Wk + k0 + lk),
                         *(const float4*)(Wk + k0 + lk + 4));
        short8 bfr = *(const short8*)(Pr + k0 + lk);
        acc = __builtin_amdgcn_mfma_f32_16x16x32_bf16(af, bfr, acc, 0, 0, 0);
    }
#pragma unroll
    for (int j = 0; j < 4; ++j) {
        int d = w * 16 + (l >> 4) * 4 + j;
        int e = nt * 16 + lr;
        gfull[(size_t)bh * 4096 + d * 64 + e] = acc[j];
    }
}

// ---------- K6: Wg[b][he][c] = sum_d Wq[h*64+d][c] * g[bh][d][e] (bf16 K-major) ----------
__global__ __launch_bounds__(256) void fold(const float* __restrict__ gfull,
                                            const float* __restrict__ W,
                                            u16* __restrict__ Wgb) {
    const int bh = blockIdx.x >> 3, cb = blockIdx.x & 7;
    const int b = bh >> 3, h = bh & 7;
    const int t = threadIdx.x;
    __shared__ float gs[4096];
    for (int i = t; i < 4096; i += 256) gs[i] = gfull[bh * 4096 + i];
    __syncthreads();
    const int c = cb * 64 + (t & 63);
    const int eg = (t >> 6) * 16;
    float acc[16];
#pragma unroll
    for (int j = 0; j < 16; ++j) acc[j] = 0.f;
    for (int d = 0; d < 64; ++d) {
        float w = W[(size_t)(h * 64 + d) * 512 + c];
#pragma unroll
        for (int j = 0; j < 16; ++j) acc[j] += w * gs[d * 64 + eg + j];
    }
#pragma unroll
    for (int j = 0; j < 16; ++j)
        Wgb[(size_t)(b * 512 + h * 64 + eg + j) * 512 + c] = f2bf(acc[j]);
}

// ---------- K7: z = scale/1024 + (x @ Wg)/1024, both operands bf16 staged ----------
__global__ __launch_bounds__(256) void out_z(const u16* __restrict__ xb,
                                             const u16* __restrict__ Wgb,
                                             float* __restrict__ z) {
    __shared__ u16 As[128 * 32];
    __shared__ u16 Bs[128 * 32];
    const int t = threadIdx.x;
    const int m0 = blockIdx.x * 128;
    const int b = blockIdx.x >> 6;
    const int n0 = blockIdx.y * 128;

    f32x4 zz = {0.f, 0.f, 0.f, 0.f};
    f32x4 acc[4][4];
    for (int i = 0; i < 4; ++i)
        for (int j = 0; j < 4; ++j) acc[i][j] = zz;

    gemm_core<512, 512>(xb + (size_t)m0 * 512,
                        Wgb + (size_t)b * 262144 + (size_t)n0 * 512, As, Bs, t, acc);

    const int l = t & 63, wv = t >> 6;
    const int lr = l & 15;
    const int wm = (wv >> 1) * 64, wn = (wv & 1) * 64;
#pragma unroll
    for (int mi = 0; mi < 4; ++mi)
#pragma unroll
        for (int ni = 0; ni < 4; ++ni) {
            int he = n0 + wn + ni * 16 + lr;
            int h = he >> 6, e = he & 63;
#pragma unroll
            for (int j = 0; j < 4; ++j) {
                int row = m0 + wm + mi * 16 + (l >> 4) * 4 + j;
                int nidx = row & 8191;
                z[((size_t)(b * 8 + h) * 8192 + nidx) * 64 + e] =
                    (acc[mi][ni][j] + 0.125f) * 0.0009765625f;
            }
        }
}

extern "C" void kernel_launch(void* const* d_in, const int* in_sizes, int n_in,
                              void* d_out, int out_size, void* d_ws, size_t ws_size,
                              hipStream_t stream) {
    const float* x = (const float*)d_in[0];   // [2,8192,512] fp32
    const float* W = (const float*)d_in[1];   // [1536,512] fp32
    float* z = (float*)d_out;                 // [2,8,8192,64] fp32

    char* ws = (char*)d_ws;
    u16* xT      = (u16*)(ws);                  // 16,777,216 B  [2][512][8192]
    u16* xb      = (u16*)(ws + 16777216);       // 16,777,216 B  [2][8192][512]
    u16* Spart   = (u16*)(ws + 33554432);       // 33,554,432 B  [2][32][512][512]
    u16* Sbf     = (u16*)(ws + 67108864);       //  1,048,576 B  [2][512][512]
    float* ssum  = (float*)(ws + 68157440);     //      4,096 B  [2][512]
    u16* wvb     = (u16*)(ws + 68161536);       //    524,288 B  [512][512]
    float* Ppart = (float*)(ws + 68685824);     //  8,388,608 B  [2][4][512][512]
    u16* Pb      = (u16*)(ws + 77074432);       //  1,048,576 B  [2][512][512]
    float* gfull = (float*)(ws + 78123008);     //    262,144 B  [16][64][64]
    u16* Wgb     = (u16*)(ws + 78385152);       //  1,048,576 B  [2][512][512]

    zero_s<<<4, 256, 0, stream>>>(ssum);
    cvt_t<<<1024, 256, 0, stream>>>(x, xT, xb, ssum);
    cvt_bf16<<<256, 256, 0, stream>>>(W + 524288, wvb, 65536);  // Wv rows
    syrk<<<1024, 256, 0, stream>>>(xT, Spart);
    reduceS<<<1024, 256, 0, stream>>>(Spart, ssum, Sbf);
    pgemm<<<128, 256, 0, stream>>>(wvb, Sbf, Ppart);
    reduceP<<<512, 256, 0, stream>>>(Ppart, Pb);
    g2<<<64, 256, 0, stream>>>(W, Pb, gfull);
    fold<<<128, 256, 0, stream>>>(gfull, W, Wgb);
    out_z<<<dim3(128, 4), 256, 0, stream>>>(xb, Wgb, z);
}

// Round 7
// 91.147 us; speedup vs baseline: 1.3092x; 1.1125x over previous
//
#include <hip/hip_runtime.h>

typedef unsigned short u16;
typedef unsigned int u32;
typedef __attribute__((ext_vector_type(8))) short short8;
typedef __attribute__((ext_vector_type(4))) float f32x4;
typedef __attribute__((ext_vector_type(4))) unsigned short ushort4v;
typedef __attribute__((ext_vector_type(4))) float float4v;

// ---------- helpers ----------
__device__ __forceinline__ float bf2f(u16 u) {
    return __uint_as_float(((u32)u) << 16);
}
__device__ __forceinline__ u16 f2bf(float f) {
    u32 u = __float_as_uint(f);
    u += 0x7FFF + ((u >> 16) & 1);   // RNE
    return (u16)(u >> 16);
}
__device__ __forceinline__ short8 cvt8(float4 a, float4 b) {
    short8 r;
    r[0] = (short)f2bf(a.x); r[1] = (short)f2bf(a.y);
    r[2] = (short)f2bf(a.z); r[3] = (short)f2bf(a.w);
    r[4] = (short)f2bf(b.x); r[5] = (short)f2bf(b.y);
    r[6] = (short)f2bf(b.z); r[7] = (short)f2bf(b.w);
    return r;
}
// async global->LDS, 16B per lane; dst wave-uniform (HW adds lane*16)
__device__ __forceinline__ void stage16(const u16* g, u16* l) {
    __builtin_amdgcn_global_load_lds(
        (const __attribute__((address_space(1))) unsigned int*)g,
        (__attribute__((address_space(3))) unsigned int*)l, 16, 0, 0);
}

// ---------- K0: cvt + transpose + row-copy + per-block column partials; Wv cvt in bid>=1024 ----------
__global__ __launch_bounds__(256) void cvt_t(const float* __restrict__ x,
                                             u16* __restrict__ xT,
                                             u16* __restrict__ xb,
                                             float* __restrict__ sp2,
                                             const float* __restrict__ W,
                                             u16* __restrict__ wvb) {
    const int bid = blockIdx.x;
    const int t = threadIdx.x;
    if (bid >= 1024) {   // Wv fp32 -> bf16 (proven cvt_bf16 body)
        const int i = (bid - 1024) * 256 + t;
        float4v v = ((const float4v*)(W + 524288))[i];
        ushort4v r;
        r[0] = f2bf(v[0]); r[1] = f2bf(v[1]); r[2] = f2bf(v[2]); r[3] = f2bf(v[3]);
        ((ushort4v*)wvb)[i] = r;
        return;
    }
    __shared__ u16 tile[64][136];   // [n][c], pad 8
    const int ct = bid & 3, nt = (bid >> 2) & 127, b = bid >> 9;
    const int r = t >> 2, c0 = (t & 3) * 32;
    const float* src = x + ((size_t)(b * 8192 + nt * 64 + r)) * 512 + ct * 128 + c0;
    short8 r8[4];
#pragma unroll
    for (int j = 0; j < 8; j += 2) {
        float4 v0 = *(const float4*)(src + j * 4);
        float4 v1 = *(const float4*)(src + j * 4 + 4);
        r8[j >> 1] = cvt8(v0, v1);
        *(short8*)(&tile[r][c0 + j * 4]) = r8[j >> 1];
    }
    // row-major bf16 copy
    u16* xbrow = xb + ((size_t)(b * 8192 + nt * 64 + r)) * 512 + ct * 128 + c0;
#pragma unroll
    for (int jj = 0; jj < 4; ++jj) *(short8*)(xbrow + jj * 8) = r8[jj];
    __syncthreads();
    const int c = t >> 1, half = t & 1;
    u16 vals[32];
    float psum = 0.f;
#pragma unroll
    for (int i = 0; i < 32; ++i) {
        vals[i] = tile[half * 32 + i][c];
        psum += bf2f(vals[i]);
    }
    u16* dst = xT + ((size_t)(b * 512 + ct * 128 + c)) * 8192 + nt * 64 + half * 32;
#pragma unroll
    for (int j = 0; j < 4; ++j)
        *(int4*)(dst + j * 8) = *(int4*)(&vals[j * 8]);
    psum += __shfl_xor(psum, 1);
    if ((t & 1) == 0)
        sp2[((size_t)(b * 128 + nt)) * 512 + ct * 128 + c] = psum;   // non-atomic partial
}

// ---------- shared GEMM core: 128x128 tile, BK=32, global_load_lds ----------
template <int STRIDE, int KLEN>
__device__ __forceinline__ void gemm_core(const u16* __restrict__ Ag,
                                          const u16* __restrict__ Bg,
                                          u16* As, u16* Bs, int t,
                                          f32x4 acc[4][4]) {
    const int wv = t >> 6, l = t & 63;
    const int lr = l & 15, lk = (l >> 4) * 8;
    const int wm = (wv >> 1) * 64, wn = (wv & 1) * 64;
    const int srow = l >> 2, scol = (l & 3) * 8;

    u16* Ad0 = As + (wv * 32) * 32;
    u16* Ad1 = As + (wv * 32 + 16) * 32;
    u16* Bd0 = Bs + (wv * 32) * 32;
    u16* Bd1 = Bs + (wv * 32 + 16) * 32;
    const u16* As0 = Ag + (size_t)(wv * 32 + srow) * STRIDE + scol;
    const u16* As1 = Ag + (size_t)(wv * 32 + 16 + srow) * STRIDE + scol;
    const u16* Bs0 = Bg + (size_t)(wv * 32 + srow) * STRIDE + scol;
    const u16* Bs1 = Bg + (size_t)(wv * 32 + 16 + srow) * STRIDE + scol;

    for (int k0 = 0; k0 < KLEN; k0 += 32) {
        stage16(As0 + k0, Ad0);
        stage16(As1 + k0, Ad1);
        stage16(Bs0 + k0, Bd0);
        stage16(Bs1 + k0, Bd1);
        __syncthreads();
        short8 af[4], bfr[4];
#pragma unroll
        for (int mi = 0; mi < 4; ++mi)
            af[mi] = *(const short8*)(As + (wm + mi * 16 + lr) * 32 + lk);
#pragma unroll
        for (int ni = 0; ni < 4; ++ni)
            bfr[ni] = *(const short8*)(Bs + (wn + ni * 16 + lr) * 32 + lk);
#pragma unroll
        for (int mi = 0; mi < 4; ++mi)
#pragma unroll
            for (int ni = 0; ni < 4; ++ni)
                acc[mi][ni] = __builtin_amdgcn_mfma_f32_16x16x32_bf16(
                    af[mi], bfr[ni], acc[mi][ni], 0, 0, 0);
        __syncthreads();
    }
}

// ---------- K1: syrk partials (16 chunks of 512 rows, round-3-proven) + ssum reduce ----------
__global__ __launch_bounds__(256) void syrk(const u16* __restrict__ xT,
                                            u16* __restrict__ Spart,
                                            const float* __restrict__ sp2,
                                            float* __restrict__ ssum) {
    const int bid = blockIdx.x, t = threadIdx.x;
    if (bid >= 512) {   // reduce sp2 -> ssum
        const int idx = (bid - 512) * 256 + t;   // [0,1024)
        const int b = idx >> 9, c = idx & 511;
        float a = 0.f;
        for (int j = 0; j < 128; ++j) a += sp2[(size_t)(b * 128 + j) * 512 + c];
        ssum[idx] = a;
        return;
    }
    __shared__ u16 As[128 * 32];
    __shared__ u16 Bs[128 * 32];
    const int nt = bid & 3, mt = (bid >> 2) & 3;
    const int ks = (bid >> 4) & 15, b = bid >> 8;
    const u16* Ag = xT + ((size_t)(b * 512 + mt * 128)) * 8192 + ks * 512;
    const u16* Bg = xT + ((size_t)(b * 512 + nt * 128)) * 8192 + ks * 512;

    f32x4 zz = {0.f, 0.f, 0.f, 0.f};
    f32x4 acc[4][4];
    for (int i = 0; i < 4; ++i)
        for (int j = 0; j < 4; ++j) acc[i][j] = zz;

    gemm_core<8192, 512>(Ag, Bg, As, Bs, t, acc);

    const int l = t & 63, wv = t >> 6;
    const int lr = l & 15;
    const int wm = (wv >> 1) * 64, wn = (wv & 1) * 64;
    u16* out = Spart + ((size_t)(b * 16 + ks)) * 262144;
#pragma unroll
    for (int mi = 0; mi < 4; ++mi)
#pragma unroll
        for (int ni = 0; ni < 4; ++ni) {
            int col = nt * 128 + wn + ni * 16 + lr;
#pragma unroll
            for (int j = 0; j < 4; ++j) {
                int row = mt * 128 + wm + mi * 16 + (l >> 4) * 4 + j;
                out[(size_t)row * 512 + col] = f2bf(acc[mi][ni][j]);
            }
        }
}

// ---------- K2: reduce partials + centering -> S' bf16 [2][512][512] ----------
__global__ __launch_bounds__(256) void reduceS(const u16* __restrict__ Spart,
                                               const float* __restrict__ s,
                                               u16* __restrict__ Sbf) {
    const int b = blockIdx.x >> 9, m = blockIdx.x & 511;
    const int t = threadIdx.x;
    const float sm = s[b * 512 + m] * (1.0f / 8192.0f);
#pragma unroll
    for (int rep = 0; rep < 2; ++rep) {
        const int n = rep * 256 + t;
        float acc = 0.f;
#pragma unroll
        for (int ks = 0; ks < 16; ++ks)
            acc += bf2f(Spart[((size_t)(b * 16 + ks)) * 262144 + (size_t)m * 512 + n]);
        acc -= sm * s[b * 512 + n];
        Sbf[(size_t)b * 262144 + (size_t)m * 512 + n] = f2bf(acc);
    }
}

// ---------- K3: P = Wv * S'_b, no K-split, write bf16 directly ----------
__global__ __launch_bounds__(256) void pgemm(const u16* __restrict__ wvb,
                                             const u16* __restrict__ Sbf,
                                             u16* __restrict__ Pb) {
    __shared__ u16 As[128 * 32];
    __shared__ u16 Bs[128 * 32];
    const int t = threadIdx.x;
    const int nt = blockIdx.x & 3, mt = (blockIdx.x >> 2) & 3, b = blockIdx.x >> 4;
    const u16* Ag = wvb + (size_t)(mt * 128) * 512;
    const u16* Bg = Sbf + (size_t)b * 262144 + (size_t)(nt * 128) * 512;

    f32x4 zz = {0.f, 0.f, 0.f, 0.f};
    f32x4 acc[4][4];
    for (int i = 0; i < 4; ++i)
        for (int j = 0; j < 4; ++j) acc[i][j] = zz;

    gemm_core<512, 512>(Ag, Bg, As, Bs, t, acc);

    const int l = t & 63, wv = t >> 6;
    const int lr = l & 15;
    const int wm = (wv >> 1) * 64, wn = (wv & 1) * 64;
    u16* out = Pb + (size_t)b * 262144;
#pragma unroll
    for (int mi = 0; mi < 4; ++mi)
#pragma unroll
        for (int ni = 0; ni < 4; ++ni) {
            int col = nt * 128 + wn + ni * 16 + lr;
#pragma unroll
            for (int j = 0; j < 4; ++j) {
                int row = mt * 128 + wm + mi * 16 + (l >> 4) * 4 + j;
                out[(size_t)row * 512 + col] = f2bf(acc[mi][ni][j]);
            }
        }
}

// ---------- K4: g[bh][d][e] = sum_c Wk[h*64+d][c] * P[b][h*64+e][c] ----------
__global__ __launch_bounds__(256) void g2(const float* __restrict__ W,
                                          const u16* __restrict__ Pb,
                                          float* __restrict__ gfull) {
    const int bh = blockIdx.x >> 2, nt = blockIdx.x & 3;
    const int b = bh >> 3, h = bh & 7;
    const int t = threadIdx.x, w = t >> 6, l = t & 63;
    const int lr = l & 15, lk = (l >> 4) * 8;
    const float* Wk = W + (size_t)(512 + h * 64 + w * 16 + lr) * 512;
    const u16* Pr = Pb + (size_t)b * 262144 + (size_t)(h * 64 + nt * 16 + lr) * 512;

    f32x4 acc = {0.f, 0.f, 0.f, 0.f};
    for (int k0 = 0; k0 < 512; k0 += 32) {
        short8 af = cvt8(*(const float4*)(Wk + k0 + lk),
                         *(const float4*)(Wk + k0 + lk + 4));
        short8 bfr = *(const short8*)(Pr + k0 + lk);
        acc = __builtin_amdgcn_mfma_f32_16x16x32_bf16(af, bfr, acc, 0, 0, 0);
    }
#pragma unroll
    for (int j = 0; j < 4; ++j) {
        int d = w * 16 + (l >> 4) * 4 + j;
        int e = nt * 16 + lr;
        gfull[(size_t)bh * 4096 + d * 64 + e] = acc[j];
    }
}

// ---------- K5: Wg[b][he][c] = sum_d Wq[h*64+d][c] * g[bh][d][e] (bf16 K-major) ----------
__global__ __launch_bounds__(256) void fold(const float* __restrict__ gfull,
                                            const float* __restrict__ W,
                                            u16* __restrict__ Wgb) {
    const int bh = blockIdx.x >> 3, cb = blockIdx.x & 7;
    const int b = bh >> 3, h = bh & 7;
    const int t = threadIdx.x;
    __shared__ float gs[4096];
    for (int i = t; i < 4096; i += 256) gs[i] = gfull[bh * 4096 + i];
    __syncthreads();
    const int c = cb * 64 + (t & 63);
    const int eg = (t >> 6) * 16;
    float acc[16];
#pragma unroll
    for (int j = 0; j < 16; ++j) acc[j] = 0.f;
    for (int d = 0; d < 64; ++d) {
        float w = W[(size_t)(h * 64 + d) * 512 + c];
#pragma unroll
        for (int j = 0; j < 16; ++j) acc[j] += w * gs[d * 64 + eg + j];
    }
#pragma unroll
    for (int j = 0; j < 16; ++j)
        Wgb[(size_t)(b * 512 + h * 64 + eg + j) * 512 + c] = f2bf(acc[j]);
}

// ---------- K6: z = scale/1024 + (x @ Wg)/1024, both operands bf16 staged ----------
__global__ __launch_bounds__(256) void out_z(const u16* __restrict__ xb,
                                             const u16* __restrict__ Wgb,
                                             float* __restrict__ z) {
    __shared__ u16 As[128 * 32];
    __shared__ u16 Bs[128 * 32];
    const int t = threadIdx.x;
    const int m0 = blockIdx.x * 128;
    const int b = blockIdx.x >> 6;
    const int n0 = blockIdx.y * 128;

    f32x4 zz = {0.f, 0.f, 0.f, 0.f};
    f32x4 acc[4][4];
    for (int i = 0; i < 4; ++i)
        for (int j = 0; j < 4; ++j) acc[i][j] = zz;

    gemm_core<512, 512>(xb + (size_t)m0 * 512,
                        Wgb + (size_t)b * 262144 + (size_t)n0 * 512, As, Bs, t, acc);

    const int l = t & 63, wv = t >> 6;
    const int lr = l & 15;
    const int wm = (wv >> 1) * 64, wn = (wv & 1) * 64;
#pragma unroll
    for (int mi = 0; mi < 4; ++mi)
#pragma unroll
        for (int ni = 0; ni < 4; ++ni) {
            int he = n0 + wn + ni * 16 + lr;
            int h = he >> 6, e = he & 63;
#pragma unroll
            for (int j = 0; j < 4; ++j) {
                int row = m0 + wm + mi * 16 + (l >> 4) * 4 + j;
                int nidx = row & 8191;
                z[((size_t)(b * 8 + h) * 8192 + nidx) * 64 + e] =
                    (acc[mi][ni][j] + 0.125f) * 0.0009765625f;
            }
        }
}

extern "C" void kernel_launch(void* const* d_in, const int* in_sizes, int n_in,
                              void* d_out, int out_size, void* d_ws, size_t ws_size,
                              hipStream_t stream) {
    const float* x = (const float*)d_in[0];   // [2,8192,512] fp32
    const float* W = (const float*)d_in[1];   // [1536,512] fp32
    float* z = (float*)d_out;                 // [2,8,8192,64] fp32

    char* ws = (char*)d_ws;
    u16* xT      = (u16*)(ws);                  // 16,777,216 B  [2][512][8192]
    u16* xb      = (u16*)(ws + 16777216);       // 16,777,216 B  [2][8192][512]
    u16* Spart   = (u16*)(ws + 33554432);       // 16,777,216 B  [2][16][512][512]
    u16* Sbf     = (u16*)(ws + 50331648);       //  1,048,576 B  [2][512][512]
    float* sp2   = (float*)(ws + 51380224);     //    524,288 B  [2][128][512]
    float* ssum  = (float*)(ws + 51904512);     //      4,096 B  [2][512]
    u16* wvb     = (u16*)(ws + 51908608);       //    524,288 B  [512][512]
    u16* Pb      = (u16*)(ws + 52432896);       //  1,048,576 B  [2][512][512]
    float* gfull = (float*)(ws + 53481472);     //    262,144 B  [16][64][64]
    u16* Wgb     = (u16*)(ws + 53743616);       //  1,048,576 B  [2][512][512]

    cvt_t<<<1280, 256, 0, stream>>>(x, xT, xb, sp2, W, wvb);
    syrk<<<516, 256, 0, stream>>>(xT, Spart, sp2, ssum);
    reduceS<<<1024, 256, 0, stream>>>(Spart, ssum, Sbf);
    pgemm<<<32, 256, 0, stream>>>(wvb, Sbf, Pb);
    g2<<<64, 256, 0, stream>>>(W, Pb, gfull);
    fold<<<128, 256, 0, stream>>>(gfull, W, Wgb);
    out_z<<<dim3(128, 4), 256, 0, stream>>>(xb, Wgb, z);
}